// Round 8
// baseline (554.952 us; speedup 1.0000x reference)
//
#include <hip/hip_runtime.h>
#include <math.h>

#define N_NODES  100000
#define N_EDGES  1600000
#define IN_F     128
#define HID      64
#define HEADS    4
#define NCLS     16
#define D1       (HEADS*HID)    // 256
#define D2       (HEADS*NCLS)   // 64

#define SCAN_CHUNK 1024
#define SCAN_NB    ((N_NODES + SCAN_CHUNK - 1) / SCAN_CHUNK)   // 98
#define N_NODES_PAD (SCAN_NB * SCAN_CHUNK)                     // 100352
#define RB1 128   // reduce-stage-1 blocks

typedef __attribute__((ext_vector_type(8))) short bf16x8_t;
typedef __attribute__((ext_vector_type(4))) float f32x4_t;

// bf16 helpers (RNE)
__device__ __forceinline__ unsigned bf16rne(float x) {
  unsigned u = __float_as_uint(x);
  return (u + 0x7fffu + ((u >> 16) & 1u)) >> 16;
}
__device__ __forceinline__ unsigned packbf2(float lo, float hi) {
  return bf16rne(lo) | (bf16rne(hi) << 16);
}
__device__ __forceinline__ float bflo(unsigned p) { return __uint_as_float(p << 16); }
__device__ __forceinline__ float bfhi(unsigned p) { return __uint_as_float(p & 0xffff0000u); }

// ============================ CSR build ============================
__global__ __launch_bounds__(256)
void k_zero4(int4* __restrict__ p, int n4) {
  int i = blockIdx.x * blockDim.x + threadIdx.x;
  if (i < n4) p[i] = make_int4(0, 0, 0, 0);
}

__global__ __launch_bounds__(256)
void k_count(const int* __restrict__ dst, int* __restrict__ cursorPad,
             int* __restrict__ rank) {
  int i = blockIdx.x * blockDim.x + threadIdx.x;
  if (i < N_EDGES) {
    int d = dst[i];
    rank[i] = atomicAdd(&cursorPad[d << 4], 1);
  }
}

__global__ __launch_bounds__(256)
void k_compact(const int* __restrict__ cursorPad, int* __restrict__ counts) {
  int i = blockIdx.x * blockDim.x + threadIdx.x;
  if (i < N_NODES_PAD) counts[i] = (i < N_NODES) ? cursorPad[i << 4] : 0;
}

__global__ __launch_bounds__(256)
void k_scanA(const int* __restrict__ counts, int* __restrict__ btot) {
  __shared__ int red[256];
  int t = threadIdx.x;
  const int4* cp = (const int4*)(counts + blockIdx.x * SCAN_CHUNK);
  int4 v = cp[t];
  red[t] = v.x + v.y + v.z + v.w;
  __syncthreads();
  for (int s = 128; s; s >>= 1) {
    if (t < s) red[t] += red[t + s];
    __syncthreads();
  }
  if (t == 0) btot[blockIdx.x] = red[0];
}

__global__ __launch_bounds__(128)
void k_scanB(const int* __restrict__ btot, int* __restrict__ bbase,
             int* __restrict__ offs) {
  __shared__ int part[128];
  int t = threadIdx.x;
  part[t] = (t < SCAN_NB) ? btot[t] : 0;
  __syncthreads();
  for (int o = 1; o < 128; o <<= 1) {
    int v = (t >= o) ? part[t - o] : 0;
    __syncthreads();
    part[t] += v;
    __syncthreads();
  }
  if (t < SCAN_NB) bbase[t] = (t == 0) ? 0 : part[t - 1];
  if (t == 0) offs[N_NODES] = N_EDGES;
}

__global__ __launch_bounds__(256)
void k_scanC(const int* __restrict__ counts, const int* __restrict__ bbase,
             int* __restrict__ offs) {
  __shared__ int part[256];
  int t = threadIdx.x;
  int gbase = blockIdx.x * SCAN_CHUNK;
  const int4* cp = (const int4*)(counts + gbase);
  int4 v = cp[t];
  int tot = v.x + v.y + v.z + v.w;
  part[t] = tot;
  __syncthreads();
  for (int o = 1; o < 256; o <<= 1) {
    int q = (t >= o) ? part[t - o] : 0;
    __syncthreads();
    part[t] += q;
    __syncthreads();
  }
  int run = bbase[blockIdx.x] + part[t] - tot;
  int i0 = gbase + t * 4;
  int o0 = run;
  int o1 = o0 + v.x;
  int o2 = o1 + v.y;
  int o3 = o2 + v.z;
  if (i0 + 0 < N_NODES) offs[i0 + 0] = o0;
  if (i0 + 1 < N_NODES) offs[i0 + 1] = o1;
  if (i0 + 2 < N_NODES) offs[i0 + 2] = o2;
  if (i0 + 3 < N_NODES) offs[i0 + 3] = o3;
}

__global__ __launch_bounds__(256)
void k_scatter(const int* __restrict__ src, const int* __restrict__ dst,
               const int* __restrict__ rank, const int* __restrict__ offs,
               int* __restrict__ csrsrc) {
  int i = blockIdx.x * blockDim.x + threadIdx.x;
  if (i < N_EDGES) {
    csrsrc[offs[dst[i]] + rank[i]] = src[i];
  }
}

// ============== weight transpose to k-contiguous bf16 ==============
__global__ __launch_bounds__(256)
void k_prepw(const float* __restrict__ W1, const float* __restrict__ W2,
             unsigned* __restrict__ W1t32, unsigned* __restrict__ W2t32) {
  int t = threadIdx.x;
  if (blockIdx.x == 0) {
    int c = t;
    const float* wp = W1 + ((c >> 6) << 13) + (c & 63);
    unsigned* op = W1t32 + c * 64;
    for (int fp = 0; fp < 64; ++fp) {
      float lo = wp[(2 * fp) << 6];
      float hi = wp[(2 * fp + 1) << 6];
      op[fp] = packbf2(lo, hi);
    }
  } else {
    int c = t & 63, fq = t >> 6;
    const float* wp = W2 + ((c >> 4) << 12) + (c & 15);
    unsigned* op = W2t32 + c * 128 + fq * 32;
    for (int fp = 0; fp < 32; ++fp) {
      int f0 = fq * 64 + 2 * fp;
      op[fp] = packbf2(wp[f0 << 4], wp[(f0 + 1) << 4]);
    }
  }
}

// ============================ GEMM 1 (MFMA) + fused scores ============================
__global__ __launch_bounds__(256)
void k_gemm1(const float* __restrict__ h, const unsigned short* __restrict__ W1t,
             const float* __restrict__ bias, const float* __restrict__ a1,
             unsigned short* __restrict__ Whb,
             float* __restrict__ sD, float* __restrict__ sS) {
  __shared__ float aLds[512];
  int t = threadIdx.x;
  aLds[t] = a1[t];
  aLds[t + 256] = a1[t + 256];
  __syncthreads();

  int wv = t >> 6;
  int lane = t & 63;
  int m = lane & 15;
  int q8 = (lane >> 4) * 8;
  int node = blockIdx.x * 64 + wv * 16 + m;
  int nclamp = node < N_NODES ? node : N_NODES - 1;

  f32x4_t acc[16] = {};
  const float* hp0 = h + (size_t)nclamp * IN_F + q8;
  #pragma unroll
  for (int ks = 0; ks < 4; ++ks) {
    int kk = ks * 32;
    float4 f0 = *(const float4*)(hp0 + kk);
    float4 f1 = *(const float4*)(hp0 + kk + 4);
    bf16x8_t bf;
    bf[0] = (short)bf16rne(f0.x); bf[1] = (short)bf16rne(f0.y);
    bf[2] = (short)bf16rne(f0.z); bf[3] = (short)bf16rne(f0.w);
    bf[4] = (short)bf16rne(f1.x); bf[5] = (short)bf16rne(f1.y);
    bf[6] = (short)bf16rne(f1.z); bf[7] = (short)bf16rne(f1.w);
    #pragma unroll
    for (int ct = 0; ct < 16; ++ct) {
      bf16x8_t af = *(const bf16x8_t*)(W1t + (ct * 16 + m) * IN_F + kk + q8);
      acc[ct] = __builtin_amdgcn_mfma_f32_16x16x32_bf16(af, bf, acc[ct], 0, 0, 0);
    }
  }
  if (node < N_NODES) {
    unsigned short* op = Whb + (size_t)node * D1;
    int quad4 = (lane >> 4) * 4;
    float pd[4] = {}, ps[4] = {};
    #pragma unroll
    for (int ct = 0; ct < 16; ++ct) {
      int c0 = ct * 16 + quad4;
      float4 bb = *(const float4*)(bias + c0);
      float v0 = acc[ct][0] + bb.x, v1 = acc[ct][1] + bb.y;
      float v2 = acc[ct][2] + bb.z, v3 = acc[ct][3] + bb.w;
      int hh = ct >> 2;
      const float* aD = &aLds[hh * 128 + (c0 & 63)];
      pd[hh] += v0 * aD[0] + v1 * aD[1] + v2 * aD[2] + v3 * aD[3];
      ps[hh] += v0 * aD[64] + v1 * aD[65] + v2 * aD[66] + v3 * aD[67];
      uint2 o;
      o.x = packbf2(v0, v1);
      o.y = packbf2(v2, v3);
      *(uint2*)(op + c0) = o;
    }
    #pragma unroll
    for (int hh = 0; hh < 4; ++hh) {
      pd[hh] += __shfl_xor(pd[hh], 16); pd[hh] += __shfl_xor(pd[hh], 32);
      ps[hh] += __shfl_xor(ps[hh], 16); ps[hh] += __shfl_xor(ps[hh], 32);
    }
    if (lane < 16) {
      ((float4*)sD)[node] = make_float4(pd[0], pd[1], pd[2], pd[3]);
      ((float4*)sS)[node] = make_float4(ps[0], ps[1], ps[2], ps[3]);
    }
  }
}

// ============================ GEMM 2 (MFMA) + fused scores ============================
__global__ __launch_bounds__(256)
void k_gemm2(const unsigned short* __restrict__ h1b, const unsigned short* __restrict__ W2t,
             const float* __restrict__ bias, const float* __restrict__ a2,
             unsigned short* __restrict__ Whb2,
             float* __restrict__ sD, float* __restrict__ sS) {
  __shared__ float aLds[128];
  int t = threadIdx.x;
  if (t < 128) aLds[t] = a2[t];
  __syncthreads();

  int wv = t >> 6;
  int lane = t & 63;
  int m = lane & 15;
  int q8 = (lane >> 4) * 8;
  int node = blockIdx.x * 64 + wv * 16 + m;
  int nclamp = node < N_NODES ? node : N_NODES - 1;

  f32x4_t acc[4] = {};
  const unsigned short* hp0 = h1b + (size_t)nclamp * D1 + q8;
  #pragma unroll
  for (int ks = 0; ks < 8; ++ks) {
    int kk = ks * 32;
    bf16x8_t bf = *(const bf16x8_t*)(hp0 + kk);
    #pragma unroll
    for (int ct = 0; ct < 4; ++ct) {
      bf16x8_t af = *(const bf16x8_t*)(W2t + (ct * 16 + m) * D1 + kk + q8);
      acc[ct] = __builtin_amdgcn_mfma_f32_16x16x32_bf16(af, bf, acc[ct], 0, 0, 0);
    }
  }
  if (node < N_NODES) {
    unsigned short* op = Whb2 + (size_t)node * D2;
    int quad4 = (lane >> 4) * 4;
    float pd[4] = {}, ps[4] = {};
    #pragma unroll
    for (int ct = 0; ct < 4; ++ct) {
      int c0 = ct * 16 + quad4;
      float4 bb = *(const float4*)(bias + c0);
      float v0 = acc[ct][0] + bb.x, v1 = acc[ct][1] + bb.y;
      float v2 = acc[ct][2] + bb.z, v3 = acc[ct][3] + bb.w;
      const float* aD = &aLds[ct * 32 + (c0 & 15)];
      pd[ct] += v0 * aD[0] + v1 * aD[1] + v2 * aD[2] + v3 * aD[3];
      ps[ct] += v0 * aD[16] + v1 * aD[17] + v2 * aD[18] + v3 * aD[19];
      uint2 o;
      o.x = packbf2(v0, v1);
      o.y = packbf2(v2, v3);
      *(uint2*)(op + c0) = o;
    }
    #pragma unroll
    for (int hh = 0; hh < 4; ++hh) {
      pd[hh] += __shfl_xor(pd[hh], 16); pd[hh] += __shfl_xor(pd[hh], 32);
      ps[hh] += __shfl_xor(ps[hh], 16); ps[hh] += __shfl_xor(ps[hh], 32);
    }
    if (lane < 16) {
      ((float4*)sD)[node] = make_float4(pd[0], pd[1], pd[2], pd[3]);
      ((float4*)sS)[node] = make_float4(ps[0], ps[1], ps[2], ps[3]);
    }
  }
}

// ============================ layer-1 aggregate ============================
__device__ __forceinline__ float lrelu(float x) { return x > 0.f ? x : 0.2f * x; }
__device__ __forceinline__ float elu(float x)   { return x > 0.f ? x : expm1f(x); }

// one wave per node; half-wave row split (32 lanes x 16B per 512B row).
// LDS edge buffers are zero-padded -> branch-free inner loop, unrolled x2
// (2 gathers in flight per lane).
__global__ __launch_bounds__(256)
void k_agg1(const int* __restrict__ offs, const int* __restrict__ csrsrc,
            const float* __restrict__ sD, const float* __restrict__ sS,
            const float* __restrict__ ab,
            const unsigned short* __restrict__ Whb, unsigned short* __restrict__ h1out) {
  __shared__ float exbuf[4][64 * 4];
  __shared__ int   offbuf[4][64];
  int wv = threadIdx.x >> 6;
  int wid = blockIdx.x * 4 + wv;
  int lane = threadIdx.x & 63;
  int g = lane >> 5;          // edge parity
  int l = lane & 31;          // 16B position within row
  int hh = l >> 3;            // head of this lane's 8 feats
  float acc[8] = {};
  float z0 = 0.f, z1 = 0.f, z2 = 0.f, z3 = 0.f;
  int beg = offs[wid], end = offs[wid + 1];
  bool nonempty = end > beg;
  const char* rowbase = (const char*)Whb + (l << 4);
  if (nonempty) {
    float4 dv = ((const float4*)sD)[wid];
    float db0 = dv.x + ab[0], db1 = dv.y + ab[1];
    float db2 = dv.z + ab[2], db3 = dv.w + ab[3];
    const float* eb = exbuf[wv];
    const int* ob = offbuf[wv];
    for (int cbeg = beg; cbeg < end; cbeg += 64) {
      int j = cbeg + lane;
      int cnt = end - cbeg; if (cnt > 64) cnt = 64;
      // staging: padded (zero weight) for lanes past end
      int sid = 0;
      float e0 = 0.f, e1 = 0.f, e2 = 0.f, e3 = 0.f;
      if (j < end) {
        sid = csrsrc[j];
        float4 sv = ((const float4*)sS)[sid];
        e0 = __expf(lrelu(db0 + sv.x));
        e1 = __expf(lrelu(db1 + sv.y));
        e2 = __expf(lrelu(db2 + sv.z));
        e3 = __expf(lrelu(db3 + sv.w));
        z0 += e0; z1 += e1; z2 += e2; z3 += e3;
      }
      offbuf[wv][lane] = sid << 9;
      *(float4*)&exbuf[wv][lane * 4] = make_float4(e0, e1, e2, e3);
      int npairs = (cnt + 1) >> 1;
      int u = 0;
      for (; u + 2 <= npairs; u += 2) {
        int i0 = 2 * u + g;
        int i1 = i0 + 2;
        float w0 = eb[i0 * 4 + hh];
        float w1 = eb[i1 * 4 + hh];
        int off0 = ob[i0];
        int off1 = ob[i1];
        uint4 p0 = *(const uint4*)(rowbase + off0);
        uint4 p1 = *(const uint4*)(rowbase + off1);
        acc[0] = fmaf(w0, __uint_as_float(p0.x << 16), acc[0]);
        acc[1] = fmaf(w0, __uint_as_float(p0.x), acc[1]);
        acc[2] = fmaf(w0, __uint_as_float(p0.y << 16), acc[2]);
        acc[3] = fmaf(w0, __uint_as_float(p0.y), acc[3]);
        acc[4] = fmaf(w0, __uint_as_float(p0.z << 16), acc[4]);
        acc[5] = fmaf(w0, __uint_as_float(p0.z), acc[5]);
        acc[6] = fmaf(w0, __uint_as_float(p0.w << 16), acc[6]);
        acc[7] = fmaf(w0, __uint_as_float(p0.w), acc[7]);
        acc[0] = fmaf(w1, __uint_as_float(p1.x << 16), acc[0]);
        acc[1] = fmaf(w1, __uint_as_float(p1.x), acc[1]);
        acc[2] = fmaf(w1, __uint_as_float(p1.y << 16), acc[2]);
        acc[3] = fmaf(w1, __uint_as_float(p1.y), acc[3]);
        acc[4] = fmaf(w1, __uint_as_float(p1.z << 16), acc[4]);
        acc[5] = fmaf(w1, __uint_as_float(p1.z), acc[5]);
        acc[6] = fmaf(w1, __uint_as_float(p1.w << 16), acc[6]);
        acc[7] = fmaf(w1, __uint_as_float(p1.w), acc[7]);
      }
      if (u < npairs) {
        int i0 = 2 * u + g;
        float w0 = eb[i0 * 4 + hh];
        int off0 = ob[i0];
        uint4 p0 = *(const uint4*)(rowbase + off0);
        acc[0] = fmaf(w0, __uint_as_float(p0.x << 16), acc[0]);
        acc[1] = fmaf(w0, __uint_as_float(p0.x), acc[1]);
        acc[2] = fmaf(w0, __uint_as_float(p0.y << 16), acc[2]);
        acc[3] = fmaf(w0, __uint_as_float(p0.y), acc[3]);
        acc[4] = fmaf(w0, __uint_as_float(p0.z << 16), acc[4]);
        acc[5] = fmaf(w0, __uint_as_float(p0.z), acc[5]);
        acc[6] = fmaf(w0, __uint_as_float(p0.w << 16), acc[6]);
        acc[7] = fmaf(w0, __uint_as_float(p0.w), acc[7]);
      }
    }
    #pragma unroll
    for (int o = 32; o; o >>= 1) {
      z0 += __shfl_xor(z0, o);
      z1 += __shfl_xor(z1, o);
      z2 += __shfl_xor(z2, o);
      z3 += __shfl_xor(z3, o);
    }
  }
  #pragma unroll
  for (int i = 0; i < 8; ++i) acc[i] += __shfl_xor(acc[i], 32);
  float z = (hh == 0) ? z0 : (hh == 1) ? z1 : (hh == 2) ? z2 : z3;
  if (!nonempty) z = 1.f;
  float inv = 1.f / z;
  if (g == 0) {
    float e0 = elu(acc[0] * inv), e1 = elu(acc[1] * inv);
    float e2 = elu(acc[2] * inv), e3 = elu(acc[3] * inv);
    float e4 = elu(acc[4] * inv), e5 = elu(acc[5] * inv);
    float e6 = elu(acc[6] * inv), e7 = elu(acc[7] * inv);
    uint4 o;
    o.x = packbf2(e0, e1);
    o.y = packbf2(e2, e3);
    o.z = packbf2(e4, e5);
    o.w = packbf2(e6, e7);
    *(uint4*)(h1out + (size_t)wid * D1 + l * 8) = o;
  }
}

// ============================ layer-2 aggregate + softmax + partial mean ====
// quarter-wave row split (16 lanes x 8B per 128B row), padded + unrolled x2
__global__ __launch_bounds__(256)
void k_agg2(const int* __restrict__ offs, const int* __restrict__ csrsrc,
            const float* __restrict__ sD, const float* __restrict__ sS,
            const float* __restrict__ ab,
            const unsigned short* __restrict__ Whb2, float* __restrict__ partials) {
  __shared__ float exbuf[4][64 * 4];
  __shared__ int   offbuf[4][64];
  __shared__ float red[4][16];
  int wv = threadIdx.x >> 6;
  int wid = blockIdx.x * 4 + wv;
  int lane = threadIdx.x & 63;
  int g = lane >> 4;          // edge offset within group of 4
  int l = lane & 15;          // 8B position within row
  int hh = l >> 2;            // head of this lane's 4 feats
  float acc[4] = {};
  float z0 = 0.f, z1 = 0.f, z2 = 0.f, z3 = 0.f;
  int beg = offs[wid], end = offs[wid + 1];
  bool nonempty = end > beg;
  const char* rowbase = (const char*)Whb2 + (l << 3);
  if (nonempty) {
    float4 dv = ((const float4*)sD)[wid];
    float db0 = dv.x + ab[0], db1 = dv.y + ab[1];
    float db2 = dv.z + ab[2], db3 = dv.w + ab[3];
    const float* eb = exbuf[wv];
    const int* ob = offbuf[wv];
    for (int cbeg = beg; cbeg < end; cbeg += 64) {
      int j = cbeg + lane;
      int cnt = end - cbeg; if (cnt > 64) cnt = 64;
      int sid = 0;
      float e0 = 0.f, e1 = 0.f, e2 = 0.f, e3 = 0.f;
      if (j < end) {
        sid = csrsrc[j];
        float4 sv = ((const float4*)sS)[sid];
        e0 = __expf(lrelu(db0 + sv.x));
        e1 = __expf(lrelu(db1 + sv.y));
        e2 = __expf(lrelu(db2 + sv.z));
        e3 = __expf(lrelu(db3 + sv.w));
        z0 += e0; z1 += e1; z2 += e2; z3 += e3;
      }
      offbuf[wv][lane] = sid << 7;
      *(float4*)&exbuf[wv][lane * 4] = make_float4(e0, e1, e2, e3);
      int nq = (cnt + 3) >> 2;
      int u = 0;
      for (; u + 2 <= nq; u += 2) {
        int i0 = 4 * u + g;
        int i1 = i0 + 4;
        float w0 = eb[i0 * 4 + hh];
        float w1 = eb[i1 * 4 + hh];
        int off0 = ob[i0];
        int off1 = ob[i1];
        uint2 p0 = *(const uint2*)(rowbase + off0);
        uint2 p1 = *(const uint2*)(rowbase + off1);
        acc[0] = fmaf(w0, __uint_as_float(p0.x << 16), acc[0]);
        acc[1] = fmaf(w0, __uint_as_float(p0.x), acc[1]);
        acc[2] = fmaf(w0, __uint_as_float(p0.y << 16), acc[2]);
        acc[3] = fmaf(w0, __uint_as_float(p0.y), acc[3]);
        acc[0] = fmaf(w1, __uint_as_float(p1.x << 16), acc[0]);
        acc[1] = fmaf(w1, __uint_as_float(p1.x), acc[1]);
        acc[2] = fmaf(w1, __uint_as_float(p1.y << 16), acc[2]);
        acc[3] = fmaf(w1, __uint_as_float(p1.y), acc[3]);
      }
      if (u < nq) {
        int i0 = 4 * u + g;
        float w0 = eb[i0 * 4 + hh];
        int off0 = ob[i0];
        uint2 p0 = *(const uint2*)(rowbase + off0);
        acc[0] = fmaf(w0, __uint_as_float(p0.x << 16), acc[0]);
        acc[1] = fmaf(w0, __uint_as_float(p0.x), acc[1]);
        acc[2] = fmaf(w0, __uint_as_float(p0.y << 16), acc[2]);
        acc[3] = fmaf(w0, __uint_as_float(p0.y), acc[3]);
      }
    }
    #pragma unroll
    for (int s = 32; s; s >>= 1) {
      z0 += __shfl_xor(z0, s);
      z1 += __shfl_xor(z1, s);
      z2 += __shfl_xor(z2, s);
      z3 += __shfl_xor(z3, s);
    }
  }
  #pragma unroll
  for (int i = 0; i < 4; ++i) {
    acc[i] += __shfl_xor(acc[i], 16);
    acc[i] += __shfl_xor(acc[i], 32);
  }
  float z = (hh == 0) ? z0 : (hh == 1) ? z1 : (hh == 2) ? z2 : z3;
  if (!nonempty) z = 1.f;
  float inv = 1.f / z;
  float val[4];
  #pragma unroll
  for (int i = 0; i < 4; ++i) val[i] = acc[i] * inv;
  #pragma unroll
  for (int i = 0; i < 4; ++i) {
    val[i] += __shfl_xor(val[i], 4);
    val[i] += __shfl_xor(val[i], 8);
    val[i] *= 0.25f;
  }
  float mx = fmaxf(fmaxf(val[0], val[1]), fmaxf(val[2], val[3]));
  mx = fmaxf(mx, __shfl_xor(mx, 1));
  mx = fmaxf(mx, __shfl_xor(mx, 2));
  float e[4];
  float ssum = 0.f;
  #pragma unroll
  for (int i = 0; i < 4; ++i) { e[i] = __expf(val[i] - mx); ssum += e[i]; }
  ssum += __shfl_xor(ssum, 1);
  ssum += __shfl_xor(ssum, 2);
  float rinv = 1.f / ssum;
  if (g == 0 && l < 4) {
    #pragma unroll
    for (int i = 0; i < 4; ++i) red[wv][l * 4 + i] = e[i] * rinv;
  }
  __syncthreads();
  if (threadIdx.x < 16) {
    partials[(size_t)blockIdx.x * 16 + threadIdx.x] =
        red[0][threadIdx.x] + red[1][threadIdx.x] +
        red[2][threadIdx.x] + red[3][threadIdx.x];
  }
}

// ============== hierarchical final reduce: 25000 -> 128 -> fc ==============
__global__ __launch_bounds__(256)
void k_reduce1(const float* __restrict__ partials, int nrows,
               float* __restrict__ out) {
  __shared__ float red[16][17];
  int t = threadIdx.x;
  int c = t & 15, rl = t >> 4;
  int per = (nrows + RB1 - 1) / RB1;
  int rbeg = blockIdx.x * per;
  int rend = rbeg + per; if (rend > nrows) rend = nrows;
  float s = 0.f;
  for (int r = rbeg + rl; r < rend; r += 16) s += partials[(size_t)r * 16 + c];
  red[rl][c] = s;
  __syncthreads();
  for (int st = 8; st; st >>= 1) {
    if (rl < st) red[rl][c] += red[rl + st][c];
    __syncthreads();
  }
  if (t < 16) out[(size_t)blockIdx.x * 16 + t] = red[0][t];
}

__global__ __launch_bounds__(256)
void k_final(const float* __restrict__ partials,
             const float* __restrict__ fcw, const float* __restrict__ fcb,
             float* __restrict__ out) {
  __shared__ float red[16][17];
  __shared__ float hg[16];
  int t = threadIdx.x;
  int c = t & 15, rl = t >> 4;
  float s = 0.f;
  for (int r = rl; r < RB1; r += 16) s += partials[(size_t)r * 16 + c];
  red[rl][c] = s;
  __syncthreads();
  for (int st = 8; st; st >>= 1) {
    if (rl < st) red[rl][c] += red[rl + st][c];
    __syncthreads();
  }
  if (t < 16) hg[t] = red[0][t] * (1.0f / N_NODES);
  __syncthreads();
  if (t < 16) {
    float acc = fcb[t];
    #pragma unroll
    for (int k = 0; k < 16; ++k) acc += hg[k] * fcw[t * 16 + k];
    out[t] = acc;
  }
}

// ============================ launcher ============================
extern "C" void kernel_launch(void* const* d_in, const int* in_sizes, int n_in,
                              void* d_out, int out_size, void* d_ws, size_t ws_size,
                              hipStream_t stream) {
  const float* h   = (const float*)d_in[0];
  const int*   src = (const int*)  d_in[1];
  const int*   dst = (const int*)  d_in[2];
  const float* W1  = (const float*)d_in[3];
  const float* b1  = (const float*)d_in[4];
  const float* a1  = (const float*)d_in[5];
  const float* ab1 = (const float*)d_in[6];
  const float* W2  = (const float*)d_in[7];
  const float* b2  = (const float*)d_in[8];
  const float* a2  = (const float*)d_in[9];
  const float* ab2 = (const float*)d_in[10];
  const float* fcw = (const float*)d_in[11];
  const float* fcb = (const float*)d_in[12];
  float* out = (float*)d_out;

  char* ws = (char*)d_ws;
  size_t off = 0;
  auto alloc = [&](size_t bytes) -> char* {
    char* p = ws + off;
    off += (bytes + 255) & ~(size_t)255;
    return p;
  };
  unsigned short* Whb1 = (unsigned short*)alloc((size_t)N_NODES * D1 * 2); // 51.2 MB
  unsigned short* h1b  = (unsigned short*)alloc((size_t)N_NODES * D1 * 2); // 51.2 MB
  unsigned short* Whb2 = (unsigned short*)alloc((size_t)N_NODES * D2 * 2); // 12.8 MB
  unsigned short* W1t  = (unsigned short*)alloc((size_t)D1 * IN_F * 2);
  unsigned short* W2t  = (unsigned short*)alloc((size_t)D2 * D1 * 2);
  float* sD1 = (float*)alloc((size_t)N_NODES * 4 * 4);
  float* sS1 = (float*)alloc((size_t)N_NODES * 4 * 4);
  float* sD2 = (float*)alloc((size_t)N_NODES * 4 * 4);
  float* sS2 = (float*)alloc((size_t)N_NODES * 4 * 4);
  int* cursorPad = (int*)alloc((size_t)N_NODES * 16 * 4);   // 6.4 MB
  int* rank   = (int*)alloc((size_t)N_EDGES * 4);           // 6.4 MB
  int* counts = (int*)alloc((size_t)N_NODES_PAD * 4);
  int* offs   = (int*)alloc((size_t)(N_NODES + 1) * 4);
  int* csrsrc = (int*)alloc((size_t)N_EDGES * 4);
  int* btot   = (int*)alloc((size_t)SCAN_NB * 4);
  int* bbase  = (int*)alloc((size_t)SCAN_NB * 4);
  const int nblk_node = (N_NODES + 3) / 4;   // 25000
  float* partials  = (float*)alloc((size_t)nblk_node * 16 * 4);
  float* partials2 = (float*)alloc((size_t)RB1 * 16 * 4);

  // --- weight transpose (bf16, k-contiguous) ---
  k_prepw<<<2, 256, 0, stream>>>(W1, W2, (unsigned*)W1t, (unsigned*)W2t);

  // --- CSR build (by dst); atomic-free scatter via fetch-add rank ---
  const int n4 = N_NODES * 4;
  k_zero4<<<(n4 + 255) / 256, 256, 0, stream>>>((int4*)cursorPad, n4);
  k_count<<<(N_EDGES + 255) / 256, 256, 0, stream>>>(dst, cursorPad, rank);
  k_compact<<<(N_NODES_PAD + 255) / 256, 256, 0, stream>>>(cursorPad, counts);
  k_scanA<<<SCAN_NB, 256, 0, stream>>>(counts, btot);
  k_scanB<<<1, 128, 0, stream>>>(btot, bbase, offs);
  k_scanC<<<SCAN_NB, 256, 0, stream>>>(counts, bbase, offs);
  k_scatter<<<(N_EDGES + 255) / 256, 256, 0, stream>>>(src, dst, rank, offs, csrsrc);

  const int gemmBlocks = (N_NODES + 63) / 64;   // 1563

  // --- layer 1 ---
  k_gemm1<<<gemmBlocks, 256, 0, stream>>>(h, W1t, b1, a1, Whb1, sD1, sS1);
  k_agg1<<<nblk_node, 256, 0, stream>>>(offs, csrsrc, sD1, sS1, ab1, Whb1, h1b);

  // --- layer 2 ---
  k_gemm2<<<gemmBlocks, 256, 0, stream>>>(h1b, W2t, b2, a2, Whb2, sD2, sS2);
  k_agg2<<<nblk_node, 256, 0, stream>>>(offs, csrsrc, sD2, sS2, ab2, Whb2, partials);

  // --- readout ---
  k_reduce1<<<RB1, 256, 0, stream>>>(partials, nblk_node, partials2);
  k_final<<<1, 256, 0, stream>>>(partials2, fcw, fcb, out);
}

// Round 9
// 478.796 us; speedup vs baseline: 1.1591x; 1.1591x over previous
//
#include <hip/hip_runtime.h>
#include <math.h>

#define N_NODES  100000
#define N_EDGES  1600000
#define IN_F     128
#define HID      64
#define HEADS    4
#define NCLS     16
#define D1       (HEADS*HID)    // 256
#define D2       (HEADS*NCLS)   // 64

#define SCAN_CHUNK 1024
#define SCAN_NB    ((N_NODES + SCAN_CHUNK - 1) / SCAN_CHUNK)   // 98
#define N_NODES_PAD (SCAN_NB * SCAN_CHUNK)                     // 100352
#define RB1 128   // reduce-stage-1 blocks

typedef __attribute__((ext_vector_type(8))) short bf16x8_t;
typedef __attribute__((ext_vector_type(4))) float f32x4_t;
typedef __attribute__((ext_vector_type(2))) float f32x2_t;

// bf16 helpers (RNE)
__device__ __forceinline__ unsigned bf16rne(float x) {
  unsigned u = __float_as_uint(x);
  return (u + 0x7fffu + ((u >> 16) & 1u)) >> 16;
}
__device__ __forceinline__ unsigned packbf2(float lo, float hi) {
  return bf16rne(lo) | (bf16rne(hi) << 16);
}
__device__ __forceinline__ float bflo(unsigned p) { return __uint_as_float(p << 16); }
__device__ __forceinline__ float bfhi(unsigned p) { return __uint_as_float(p & 0xffff0000u); }

// ============================ CSR build ============================
__global__ __launch_bounds__(256)
void k_zero4(int4* __restrict__ p, int n4) {
  int i = blockIdx.x * blockDim.x + threadIdx.x;
  if (i < n4) p[i] = make_int4(0, 0, 0, 0);
}

__global__ __launch_bounds__(256)
void k_count(const int* __restrict__ dst, int* __restrict__ cursorPad,
             int* __restrict__ rank) {
  int i = blockIdx.x * blockDim.x + threadIdx.x;
  if (i < N_EDGES) {
    int d = dst[i];
    rank[i] = atomicAdd(&cursorPad[d << 4], 1);
  }
}

__global__ __launch_bounds__(256)
void k_compact(const int* __restrict__ cursorPad, int* __restrict__ counts) {
  int i = blockIdx.x * blockDim.x + threadIdx.x;
  if (i < N_NODES_PAD) counts[i] = (i < N_NODES) ? cursorPad[i << 4] : 0;
}

__global__ __launch_bounds__(256)
void k_scanA(const int* __restrict__ counts, int* __restrict__ btot) {
  __shared__ int red[256];
  int t = threadIdx.x;
  const int4* cp = (const int4*)(counts + blockIdx.x * SCAN_CHUNK);
  int4 v = cp[t];
  red[t] = v.x + v.y + v.z + v.w;
  __syncthreads();
  for (int s = 128; s; s >>= 1) {
    if (t < s) red[t] += red[t + s];
    __syncthreads();
  }
  if (t == 0) btot[blockIdx.x] = red[0];
}

__global__ __launch_bounds__(128)
void k_scanB(const int* __restrict__ btot, int* __restrict__ bbase,
             int* __restrict__ offs) {
  __shared__ int part[128];
  int t = threadIdx.x;
  part[t] = (t < SCAN_NB) ? btot[t] : 0;
  __syncthreads();
  for (int o = 1; o < 128; o <<= 1) {
    int v = (t >= o) ? part[t - o] : 0;
    __syncthreads();
    part[t] += v;
    __syncthreads();
  }
  if (t < SCAN_NB) bbase[t] = (t == 0) ? 0 : part[t - 1];
  if (t == 0) offs[N_NODES] = N_EDGES;
}

__global__ __launch_bounds__(256)
void k_scanC(const int* __restrict__ counts, const int* __restrict__ bbase,
             int* __restrict__ offs) {
  __shared__ int part[256];
  int t = threadIdx.x;
  int gbase = blockIdx.x * SCAN_CHUNK;
  const int4* cp = (const int4*)(counts + gbase);
  int4 v = cp[t];
  int tot = v.x + v.y + v.z + v.w;
  part[t] = tot;
  __syncthreads();
  for (int o = 1; o < 256; o <<= 1) {
    int q = (t >= o) ? part[t - o] : 0;
    __syncthreads();
    part[t] += q;
    __syncthreads();
  }
  int run = bbase[blockIdx.x] + part[t] - tot;
  int i0 = gbase + t * 4;
  int o0 = run;
  int o1 = o0 + v.x;
  int o2 = o1 + v.y;
  int o3 = o2 + v.z;
  if (i0 + 0 < N_NODES) offs[i0 + 0] = o0;
  if (i0 + 1 < N_NODES) offs[i0 + 1] = o1;
  if (i0 + 2 < N_NODES) offs[i0 + 2] = o2;
  if (i0 + 3 < N_NODES) offs[i0 + 3] = o3;
}

__global__ __launch_bounds__(256)
void k_scatter(const int* __restrict__ src, const int* __restrict__ dst,
               const int* __restrict__ rank, const int* __restrict__ offs,
               int* __restrict__ csrsrc) {
  int i = blockIdx.x * blockDim.x + threadIdx.x;
  if (i < N_EDGES) {
    csrsrc[offs[dst[i]] + rank[i]] = src[i];
  }
}

// ============== weight transpose to k-contiguous bf16 ==============
__global__ __launch_bounds__(256)
void k_prepw(const float* __restrict__ W1, const float* __restrict__ W2,
             unsigned* __restrict__ W1t32, unsigned* __restrict__ W2t32) {
  int t = threadIdx.x;
  if (blockIdx.x == 0) {
    int c = t;
    const float* wp = W1 + ((c >> 6) << 13) + (c & 63);
    unsigned* op = W1t32 + c * 64;
    for (int fp = 0; fp < 64; ++fp) {
      float lo = wp[(2 * fp) << 6];
      float hi = wp[(2 * fp + 1) << 6];
      op[fp] = packbf2(lo, hi);
    }
  } else {
    int c = t & 63, fq = t >> 6;
    const float* wp = W2 + ((c >> 4) << 12) + (c & 15);
    unsigned* op = W2t32 + c * 128 + fq * 32;
    for (int fp = 0; fp < 32; ++fp) {
      int f0 = fq * 64 + 2 * fp;
      op[fp] = packbf2(wp[f0 << 4], wp[(f0 + 1) << 4]);
    }
  }
}

// ============================ GEMM 1 (MFMA) + fused scores ============================
// Wh8[n][256] fp8-e4m3 for the edge gather; scores from fp32 accumulators.
__global__ __launch_bounds__(256)
void k_gemm1(const float* __restrict__ h, const unsigned short* __restrict__ W1t,
             const float* __restrict__ bias, const float* __restrict__ a1,
             unsigned char* __restrict__ Wh8,
             float* __restrict__ sD, float* __restrict__ sS) {
  __shared__ float aLds[512];
  int t = threadIdx.x;
  aLds[t] = a1[t];
  aLds[t + 256] = a1[t + 256];
  __syncthreads();

  int wv = t >> 6;
  int lane = t & 63;
  int m = lane & 15;
  int q8 = (lane >> 4) * 8;
  int node = blockIdx.x * 64 + wv * 16 + m;
  int nclamp = node < N_NODES ? node : N_NODES - 1;

  f32x4_t acc[16] = {};
  const float* hp0 = h + (size_t)nclamp * IN_F + q8;
  #pragma unroll
  for (int ks = 0; ks < 4; ++ks) {
    int kk = ks * 32;
    float4 f0 = *(const float4*)(hp0 + kk);
    float4 f1 = *(const float4*)(hp0 + kk + 4);
    bf16x8_t bf;
    bf[0] = (short)bf16rne(f0.x); bf[1] = (short)bf16rne(f0.y);
    bf[2] = (short)bf16rne(f0.z); bf[3] = (short)bf16rne(f0.w);
    bf[4] = (short)bf16rne(f1.x); bf[5] = (short)bf16rne(f1.y);
    bf[6] = (short)bf16rne(f1.z); bf[7] = (short)bf16rne(f1.w);
    #pragma unroll
    for (int ct = 0; ct < 16; ++ct) {
      bf16x8_t af = *(const bf16x8_t*)(W1t + (ct * 16 + m) * IN_F + kk + q8);
      acc[ct] = __builtin_amdgcn_mfma_f32_16x16x32_bf16(af, bf, acc[ct], 0, 0, 0);
    }
  }
  if (node < N_NODES) {
    unsigned char* op = Wh8 + (size_t)node * D1;
    int quad4 = (lane >> 4) * 4;
    float pd[4] = {}, ps[4] = {};
    #pragma unroll
    for (int ct = 0; ct < 16; ++ct) {
      int c0 = ct * 16 + quad4;
      float4 bb = *(const float4*)(bias + c0);
      float v0 = acc[ct][0] + bb.x, v1 = acc[ct][1] + bb.y;
      float v2 = acc[ct][2] + bb.z, v3 = acc[ct][3] + bb.w;
      int hh = ct >> 2;
      const float* aD = &aLds[hh * 128 + (c0 & 63)];
      pd[hh] += v0 * aD[0] + v1 * aD[1] + v2 * aD[2] + v3 * aD[3];
      ps[hh] += v0 * aD[64] + v1 * aD[65] + v2 * aD[66] + v3 * aD[67];
      int pk = __builtin_amdgcn_cvt_pk_fp8_f32(v0, v1, 0, false);
      pk = __builtin_amdgcn_cvt_pk_fp8_f32(v2, v3, pk, true);
      *(unsigned*)(op + c0) = (unsigned)pk;
    }
    #pragma unroll
    for (int hh = 0; hh < 4; ++hh) {
      pd[hh] += __shfl_xor(pd[hh], 16); pd[hh] += __shfl_xor(pd[hh], 32);
      ps[hh] += __shfl_xor(ps[hh], 16); ps[hh] += __shfl_xor(ps[hh], 32);
    }
    if (lane < 16) {
      ((float4*)sD)[node] = make_float4(pd[0], pd[1], pd[2], pd[3]);
      ((float4*)sS)[node] = make_float4(ps[0], ps[1], ps[2], ps[3]);
    }
  }
}

// ============================ GEMM 2 (MFMA) + fused scores ============================
__global__ __launch_bounds__(256)
void k_gemm2(const unsigned short* __restrict__ h1b, const unsigned short* __restrict__ W2t,
             const float* __restrict__ bias, const float* __restrict__ a2,
             unsigned short* __restrict__ Whb2,
             float* __restrict__ sD, float* __restrict__ sS) {
  __shared__ float aLds[128];
  int t = threadIdx.x;
  if (t < 128) aLds[t] = a2[t];
  __syncthreads();

  int wv = t >> 6;
  int lane = t & 63;
  int m = lane & 15;
  int q8 = (lane >> 4) * 8;
  int node = blockIdx.x * 64 + wv * 16 + m;
  int nclamp = node < N_NODES ? node : N_NODES - 1;

  f32x4_t acc[4] = {};
  const unsigned short* hp0 = h1b + (size_t)nclamp * D1 + q8;
  #pragma unroll
  for (int ks = 0; ks < 8; ++ks) {
    int kk = ks * 32;
    bf16x8_t bf = *(const bf16x8_t*)(hp0 + kk);
    #pragma unroll
    for (int ct = 0; ct < 4; ++ct) {
      bf16x8_t af = *(const bf16x8_t*)(W2t + (ct * 16 + m) * D1 + kk + q8);
      acc[ct] = __builtin_amdgcn_mfma_f32_16x16x32_bf16(af, bf, acc[ct], 0, 0, 0);
    }
  }
  if (node < N_NODES) {
    unsigned short* op = Whb2 + (size_t)node * D2;
    int quad4 = (lane >> 4) * 4;
    float pd[4] = {}, ps[4] = {};
    #pragma unroll
    for (int ct = 0; ct < 4; ++ct) {
      int c0 = ct * 16 + quad4;
      float4 bb = *(const float4*)(bias + c0);
      float v0 = acc[ct][0] + bb.x, v1 = acc[ct][1] + bb.y;
      float v2 = acc[ct][2] + bb.z, v3 = acc[ct][3] + bb.w;
      const float* aD = &aLds[ct * 32 + (c0 & 15)];
      pd[ct] += v0 * aD[0] + v1 * aD[1] + v2 * aD[2] + v3 * aD[3];
      ps[ct] += v0 * aD[16] + v1 * aD[17] + v2 * aD[18] + v3 * aD[19];
      uint2 o;
      o.x = packbf2(v0, v1);
      o.y = packbf2(v2, v3);
      *(uint2*)(op + c0) = o;
    }
    #pragma unroll
    for (int hh = 0; hh < 4; ++hh) {
      pd[hh] += __shfl_xor(pd[hh], 16); pd[hh] += __shfl_xor(pd[hh], 32);
      ps[hh] += __shfl_xor(ps[hh], 16); ps[hh] += __shfl_xor(ps[hh], 32);
    }
    if (lane < 16) {
      ((float4*)sD)[node] = make_float4(pd[0], pd[1], pd[2], pd[3]);
      ((float4*)sS)[node] = make_float4(ps[0], ps[1], ps[2], ps[3]);
    }
  }
}

// ============================ layer-1 aggregate ============================
__device__ __forceinline__ float lrelu(float x) { return x > 0.f ? x : 0.2f * x; }
__device__ __forceinline__ float elu(float x)   { return x > 0.f ? x : expm1f(x); }

// one wave per node; half-wave row split: 32 lanes x 8B cover one 256B fp8 row,
// two wave halves process consecutive edges. LDS buffers zero-padded (branch-free
// inner loop, weight 0 on pad slots -> contributes nothing).
__global__ __launch_bounds__(256)
void k_agg1(const int* __restrict__ offs, const int* __restrict__ csrsrc,
            const float* __restrict__ sD, const float* __restrict__ sS,
            const float* __restrict__ ab,
            const unsigned char* __restrict__ Wh8, unsigned short* __restrict__ h1out) {
  __shared__ float exbuf[4][64 * 4];
  __shared__ int   offbuf[4][64];
  int wv = threadIdx.x >> 6;
  int wid = blockIdx.x * 4 + wv;
  int lane = threadIdx.x & 63;
  int g = lane >> 5;          // edge parity
  int l = lane & 31;          // 8B position within 256B row
  int hh = l >> 3;            // head of this lane's 8 feats
  float acc[8] = {};
  float z0 = 0.f, z1 = 0.f, z2 = 0.f, z3 = 0.f;
  int beg = offs[wid], end = offs[wid + 1];
  bool nonempty = end > beg;
  const char* rowbase = (const char*)Wh8 + (l << 3);
  if (nonempty) {
    float4 dv = ((const float4*)sD)[wid];
    float db0 = dv.x + ab[0], db1 = dv.y + ab[1];
    float db2 = dv.z + ab[2], db3 = dv.w + ab[3];
    const float* eb = exbuf[wv];
    const int* ob = offbuf[wv];
    for (int cbeg = beg; cbeg < end; cbeg += 64) {
      int j = cbeg + lane;
      int cnt = end - cbeg; if (cnt > 64) cnt = 64;
      int sid = 0;
      float e0 = 0.f, e1 = 0.f, e2 = 0.f, e3 = 0.f;
      if (j < end) {
        sid = csrsrc[j];
        float4 sv = ((const float4*)sS)[sid];
        e0 = __expf(lrelu(db0 + sv.x));
        e1 = __expf(lrelu(db1 + sv.y));
        e2 = __expf(lrelu(db2 + sv.z));
        e3 = __expf(lrelu(db3 + sv.w));
        z0 += e0; z1 += e1; z2 += e2; z3 += e3;
      }
      offbuf[wv][lane] = sid << 8;   // fp8 row byte offset
      *(float4*)&exbuf[wv][lane * 4] = make_float4(e0, e1, e2, e3);
      int npairs = (cnt + 1) >> 1;
      for (int u = 0; u < npairs; ++u) {
        int i0 = 2 * u + g;
        float w = eb[i0 * 4 + hh];
        int off = ob[i0];
        uint2 p = *(const uint2*)(rowbase + off);
        f32x2_t d0 = __builtin_amdgcn_cvt_pk_f32_fp8(p.x, false);
        f32x2_t d1 = __builtin_amdgcn_cvt_pk_f32_fp8(p.x, true);
        f32x2_t d2 = __builtin_amdgcn_cvt_pk_f32_fp8(p.y, false);
        f32x2_t d3 = __builtin_amdgcn_cvt_pk_f32_fp8(p.y, true);
        acc[0] = fmaf(w, d0[0], acc[0]);
        acc[1] = fmaf(w, d0[1], acc[1]);
        acc[2] = fmaf(w, d1[0], acc[2]);
        acc[3] = fmaf(w, d1[1], acc[3]);
        acc[4] = fmaf(w, d2[0], acc[4]);
        acc[5] = fmaf(w, d2[1], acc[5]);
        acc[6] = fmaf(w, d3[0], acc[6]);
        acc[7] = fmaf(w, d3[1], acc[7]);
      }
    }
    #pragma unroll
    for (int o = 32; o; o >>= 1) {
      z0 += __shfl_xor(z0, o);
      z1 += __shfl_xor(z1, o);
      z2 += __shfl_xor(z2, o);
      z3 += __shfl_xor(z3, o);
    }
  }
  #pragma unroll
  for (int i = 0; i < 8; ++i) acc[i] += __shfl_xor(acc[i], 32);
  float z = (hh == 0) ? z0 : (hh == 1) ? z1 : (hh == 2) ? z2 : z3;
  if (!nonempty) z = 1.f;
  float inv = 1.f / z;
  if (g == 0) {
    float e0 = elu(acc[0] * inv), e1 = elu(acc[1] * inv);
    float e2 = elu(acc[2] * inv), e3 = elu(acc[3] * inv);
    float e4 = elu(acc[4] * inv), e5 = elu(acc[5] * inv);
    float e6 = elu(acc[6] * inv), e7 = elu(acc[7] * inv);
    uint4 o;
    o.x = packbf2(e0, e1);
    o.y = packbf2(e2, e3);
    o.z = packbf2(e4, e5);
    o.w = packbf2(e6, e7);
    *(uint4*)(h1out + (size_t)wid * D1 + l * 8) = o;
  }
}

// ============================ layer-2 aggregate + softmax + partial mean ====
// quarter-wave row split (16 lanes x 8B per 128B row)  — R7 (519us) form
__global__ __launch_bounds__(256)
void k_agg2(const int* __restrict__ offs, const int* __restrict__ csrsrc,
            const float* __restrict__ sD, const float* __restrict__ sS,
            const float* __restrict__ ab,
            const unsigned short* __restrict__ Whb2, float* __restrict__ partials) {
  __shared__ float exbuf[4][64 * 4];
  __shared__ int   offbuf[4][64];
  __shared__ float red[4][16];
  int wv = threadIdx.x >> 6;
  int wid = blockIdx.x * 4 + wv;
  int lane = threadIdx.x & 63;
  int g = lane >> 4;          // edge offset within group of 4
  int l = lane & 15;          // 8B position within row
  int hh = l >> 2;            // head of this lane's 4 feats
  float acc[4] = {};
  float z0 = 0.f, z1 = 0.f, z2 = 0.f, z3 = 0.f;
  int beg = offs[wid], end = offs[wid + 1];
  bool nonempty = end > beg;
  if (nonempty) {
    float4 dv = ((const float4*)sD)[wid];
    float db0 = dv.x + ab[0], db1 = dv.y + ab[1];
    float db2 = dv.z + ab[2], db3 = dv.w + ab[3];
    const float* eb = exbuf[wv];
    const int* ob = offbuf[wv];
    for (int cbeg = beg; cbeg < end; cbeg += 64) {
      int j = cbeg + lane;
      int cnt = end - cbeg; if (cnt > 64) cnt = 64;
      if (j < end) {
        int sid = csrsrc[j];
        float4 sv = ((const float4*)sS)[sid];
        float e0 = __expf(lrelu(db0 + sv.x));
        float e1 = __expf(lrelu(db1 + sv.y));
        float e2 = __expf(lrelu(db2 + sv.z));
        float e3 = __expf(lrelu(db3 + sv.w));
        z0 += e0; z1 += e1; z2 += e2; z3 += e3;
        offbuf[wv][lane] = sid << 7;
        *(float4*)&exbuf[wv][lane * 4] = make_float4(e0, e1, e2, e3);
      }
      int iters = (cnt + 3) >> 2;
      for (int it = 0; it < iters; ++it) {
        int qq = 4 * it + g;
        int idx = qq < cnt ? qq : cnt - 1;
        float w = eb[idx * 4 + hh];
        if (qq >= cnt) w = 0.f;
        int off = ob[idx];
        uint2 p = *(const uint2*)((const char*)Whb2 + off + (l << 3));
        acc[0] = fmaf(w, __uint_as_float(p.x << 16), acc[0]);
        acc[1] = fmaf(w, __uint_as_float(p.x), acc[1]);
        acc[2] = fmaf(w, __uint_as_float(p.y << 16), acc[2]);
        acc[3] = fmaf(w, __uint_as_float(p.y), acc[3]);
      }
    }
    #pragma unroll
    for (int s = 32; s; s >>= 1) {
      z0 += __shfl_xor(z0, s);
      z1 += __shfl_xor(z1, s);
      z2 += __shfl_xor(z2, s);
      z3 += __shfl_xor(z3, s);
    }
  }
  #pragma unroll
  for (int i = 0; i < 4; ++i) {
    acc[i] += __shfl_xor(acc[i], 16);
    acc[i] += __shfl_xor(acc[i], 32);
  }
  float z = (hh == 0) ? z0 : (hh == 1) ? z1 : (hh == 2) ? z2 : z3;
  if (!nonempty) z = 1.f;
  float inv = 1.f / z;
  float val[4];
  #pragma unroll
  for (int i = 0; i < 4; ++i) val[i] = acc[i] * inv;
  #pragma unroll
  for (int i = 0; i < 4; ++i) {
    val[i] += __shfl_xor(val[i], 4);
    val[i] += __shfl_xor(val[i], 8);
    val[i] *= 0.25f;
  }
  float mx = fmaxf(fmaxf(val[0], val[1]), fmaxf(val[2], val[3]));
  mx = fmaxf(mx, __shfl_xor(mx, 1));
  mx = fmaxf(mx, __shfl_xor(mx, 2));
  float e[4];
  float ssum = 0.f;
  #pragma unroll
  for (int i = 0; i < 4; ++i) { e[i] = __expf(val[i] - mx); ssum += e[i]; }
  ssum += __shfl_xor(ssum, 1);
  ssum += __shfl_xor(ssum, 2);
  float rinv = 1.f / ssum;
  if (g == 0 && l < 4) {
    #pragma unroll
    for (int i = 0; i < 4; ++i) red[wv][l * 4 + i] = e[i] * rinv;
  }
  __syncthreads();
  if (threadIdx.x < 16) {
    partials[(size_t)blockIdx.x * 16 + threadIdx.x] =
        red[0][threadIdx.x] + red[1][threadIdx.x] +
        red[2][threadIdx.x] + red[3][threadIdx.x];
  }
}

// ============== hierarchical final reduce: 25000 -> 128 -> fc ==============
__global__ __launch_bounds__(256)
void k_reduce1(const float* __restrict__ partials, int nrows,
               float* __restrict__ out) {
  __shared__ float red[16][17];
  int t = threadIdx.x;
  int c = t & 15, rl = t >> 4;
  int per = (nrows + RB1 - 1) / RB1;
  int rbeg = blockIdx.x * per;
  int rend = rbeg + per; if (rend > nrows) rend = nrows;
  float s = 0.f;
  for (int r = rbeg + rl; r < rend; r += 16) s += partials[(size_t)r * 16 + c];
  red[rl][c] = s;
  __syncthreads();
  for (int st = 8; st; st >>= 1) {
    if (rl < st) red[rl][c] += red[rl + st][c];
    __syncthreads();
  }
  if (t < 16) out[(size_t)blockIdx.x * 16 + t] = red[0][t];
}

__global__ __launch_bounds__(256)
void k_final(const float* __restrict__ partials,
             const float* __restrict__ fcw, const float* __restrict__ fcb,
             float* __restrict__ out) {
  __shared__ float red[16][17];
  __shared__ float hg[16];
  int t = threadIdx.x;
  int c = t & 15, rl = t >> 4;
  float s = 0.f;
  for (int r = rl; r < RB1; r += 16) s += partials[(size_t)r * 16 + c];
  red[rl][c] = s;
  __syncthreads();
  for (int st = 8; st; st >>= 1) {
    if (rl < st) red[rl][c] += red[rl + st][c];
    __syncthreads();
  }
  if (t < 16) hg[t] = red[0][t] * (1.0f / N_NODES);
  __syncthreads();
  if (t < 16) {
    float acc = fcb[t];
    #pragma unroll
    for (int k = 0; k < 16; ++k) acc += hg[k] * fcw[t * 16 + k];
    out[t] = acc;
  }
}

// ============================ launcher ============================
extern "C" void kernel_launch(void* const* d_in, const int* in_sizes, int n_in,
                              void* d_out, int out_size, void* d_ws, size_t ws_size,
                              hipStream_t stream) {
  const float* h   = (const float*)d_in[0];
  const int*   src = (const int*)  d_in[1];
  const int*   dst = (const int*)  d_in[2];
  const float* W1  = (const float*)d_in[3];
  const float* b1  = (const float*)d_in[4];
  const float* a1  = (const float*)d_in[5];
  const float* ab1 = (const float*)d_in[6];
  const float* W2  = (const float*)d_in[7];
  const float* b2  = (const float*)d_in[8];
  const float* a2  = (const float*)d_in[9];
  const float* ab2 = (const float*)d_in[10];
  const float* fcw = (const float*)d_in[11];
  const float* fcb = (const float*)d_in[12];
  float* out = (float*)d_out;

  char* ws = (char*)d_ws;
  size_t off = 0;
  auto alloc = [&](size_t bytes) -> char* {
    char* p = ws + off;
    off += (bytes + 255) & ~(size_t)255;
    return p;
  };
  unsigned char*  Wh8  = (unsigned char*)alloc((size_t)N_NODES * D1);      // 25.6 MB fp8
  unsigned short* h1b  = (unsigned short*)alloc((size_t)N_NODES * D1 * 2); // 51.2 MB
  unsigned short* Whb2 = (unsigned short*)alloc((size_t)N_NODES * D2 * 2); // 12.8 MB
  unsigned short* W1t  = (unsigned short*)alloc((size_t)D1 * IN_F * 2);
  unsigned short* W2t  = (unsigned short*)alloc((size_t)D2 * D1 * 2);
  float* sD1 = (float*)alloc((size_t)N_NODES * 4 * 4);
  float* sS1 = (float*)alloc((size_t)N_NODES * 4 * 4);
  float* sD2 = (float*)alloc((size_t)N_NODES * 4 * 4);
  float* sS2 = (float*)alloc((size_t)N_NODES * 4 * 4);
  int* cursorPad = (int*)alloc((size_t)N_NODES * 16 * 4);   // 6.4 MB
  int* rank   = (int*)alloc((size_t)N_EDGES * 4);           // 6.4 MB
  int* counts = (int*)alloc((size_t)N_NODES_PAD * 4);
  int* offs   = (int*)alloc((size_t)(N_NODES + 1) * 4);
  int* csrsrc = (int*)alloc((size_t)N_EDGES * 4);
  int* btot   = (int*)alloc((size_t)SCAN_NB * 4);
  int* bbase  = (int*)alloc((size_t)SCAN_NB * 4);
  const int nblk_node = (N_NODES + 3) / 4;   // 25000
  float* partials  = (float*)alloc((size_t)nblk_node * 16 * 4);
  float* partials2 = (float*)alloc((size_t)RB1 * 16 * 4);

  // --- weight transpose (bf16, k-contiguous) ---
  k_prepw<<<2, 256, 0, stream>>>(W1, W2, (unsigned*)W1t, (unsigned*)W2t);

  // --- CSR build (by dst); atomic-free scatter via fetch-add rank ---
  const int n4 = N_NODES * 4;
  k_zero4<<<(n4 + 255) / 256, 256, 0, stream>>>((int4*)cursorPad, n4);
  k_count<<<(N_EDGES + 255) / 256, 256, 0, stream>>>(dst, cursorPad, rank);
  k_compact<<<(N_NODES_PAD + 255) / 256, 256, 0, stream>>>(cursorPad, counts);
  k_scanA<<<SCAN_NB, 256, 0, stream>>>(counts, btot);
  k_scanB<<<1, 128, 0, stream>>>(btot, bbase, offs);
  k_scanC<<<SCAN_NB, 256, 0, stream>>>(counts, bbase, offs);
  k_scatter<<<(N_EDGES + 255) / 256, 256, 0, stream>>>(src, dst, rank, offs, csrsrc);

  const int gemmBlocks = (N_NODES + 63) / 64;   // 1563

  // --- layer 1 ---
  k_gemm1<<<gemmBlocks, 256, 0, stream>>>(h, W1t, b1, a1, Wh8, sD1, sS1);
  k_agg1<<<nblk_node, 256, 0, stream>>>(offs, csrsrc, sD1, sS1, ab1, Wh8, h1b);

  // --- layer 2 ---
  k_gemm2<<<gemmBlocks, 256, 0, stream>>>(h1b, W2t, b2, a2, Whb2, sD2, sS2);
  k_agg2<<<nblk_node, 256, 0, stream>>>(offs, csrsrc, sD2, sS2, ab2, Whb2, partials);

  // --- readout ---
  k_reduce1<<<RB1, 256, 0, stream>>>(partials, nblk_node, partials2);
  k_final<<<1, 256, 0, stream>>>(partials2, fcw, fcb, out);
}